// Round 8
// baseline (3366.013 us; speedup 1.0000x reference)
//
#include <hip/hip_runtime.h>

// Problem constants (fixed by the reference)
#define NN 20000      // nodes
#define EE 240000     // real edges
#define ETOTAL 260000 // edges + self loops
#define DIN 768
#define DD 256
#define NT 9          // tags
// heads = 4, DH = 64

__device__ __forceinline__ unsigned fenc(float x) {
  unsigned u = __float_as_uint(x);
  return (u & 0x80000000u) ? ~u : (u | 0x80000000u);
}
__device__ __forceinline__ float fdec(unsigned e) {
  unsigned u = (e & 0x80000000u) ? (e ^ 0x80000000u) : ~e;
  return __uint_as_float(u);
}
__device__ __forceinline__ float gelu_f(float x) {
  return 0.5f * x * (1.0f + erff(x * 0.70710678118654752440f));
}

// ---------------- GEMM: C = act(A@B + bias [+ addc]) ----------------
// A: MxK row-major, B: KxN row-major, C: MxN. Requires N%64==0, K%32==0.
// act: 0 = none, 1 = gelu, 2 = bn(g,b) then relu
// 64x64 tile, 4x4/thread (measured best of {64x64, 128x64} on this shape).
__global__ __launch_bounds__(256) void gemm_k(
    const float* __restrict__ A, const float* __restrict__ B,
    const float* __restrict__ bias, const float* __restrict__ addc,
    const float* __restrict__ bng, const float* __restrict__ bnb,
    float* __restrict__ C, int M, int K, int N, int act)
{
  __shared__ float As[32][64];   // transposed A tile: As[k][m]
  __shared__ float Bs[32][64];   // Bs[k][n]
  const int tid = threadIdx.x;
  const int tx = tid & 15, ty = tid >> 4;
  const int m0 = blockIdx.y * 64, n0 = blockIdx.x * 64;
  float acc[4][4];
#pragma unroll
  for (int i = 0; i < 4; ++i)
#pragma unroll
    for (int j = 0; j < 4; ++j) acc[i][j] = 0.f;

  for (int kk = 0; kk < K; kk += 32) {
#pragma unroll
    for (int L = tid; L < 512; L += 256) {   // A tile: 64 rows x 8 float4
      int r = L >> 3, c4 = L & 7;
      int gm = m0 + r;
      float4 v = make_float4(0.f, 0.f, 0.f, 0.f);
      if (gm < M) v = *(const float4*)(A + (size_t)gm * K + kk + c4 * 4);
      As[c4 * 4 + 0][r] = v.x; As[c4 * 4 + 1][r] = v.y;
      As[c4 * 4 + 2][r] = v.z; As[c4 * 4 + 3][r] = v.w;
    }
#pragma unroll
    for (int L = tid; L < 512; L += 256) {   // B tile: 32 rows x 16 float4
      int r = L >> 4, c4 = L & 15;
      *(float4*)&Bs[r][c4 * 4] = *(const float4*)(B + (size_t)(kk + r) * N + n0 + c4 * 4);
    }
    __syncthreads();
#pragma unroll
    for (int k = 0; k < 32; ++k) {
      float a[4], b[4];
      *(float4*)a = *(const float4*)&As[k][ty * 4];
      *(float4*)b = *(const float4*)&Bs[k][tx * 4];
#pragma unroll
      for (int i = 0; i < 4; ++i)
#pragma unroll
        for (int j = 0; j < 4; ++j) acc[i][j] += a[i] * b[j];
    }
    __syncthreads();
  }
  const float bnc = 0.99999500003749968752f;  // 1/sqrt(1+1e-5)
#pragma unroll
  for (int i = 0; i < 4; ++i) {
    int gm = m0 + ty * 4 + i;
    if (gm >= M) continue;
    float o[4];
#pragma unroll
    for (int j = 0; j < 4; ++j) {
      int n = n0 + tx * 4 + j;
      float x = acc[i][j];
      if (bias) x += bias[n];
      if (addc) x += addc[(size_t)gm * N + n];
      if (act == 1) x = gelu_f(x);
      else if (act == 2) { x = x * (bng[n] * bnc) + bnb[n]; x = fmaxf(x, 0.f); }
      o[j] = x;
    }
    *(float4*)(C + (size_t)gm * N + n0 + tx * 4) = *(const float4*)o;
  }
}

// ---------------- per-layer edge-type tables (9 types) ----------------
__global__ __launch_bounds__(256) void edge_tables_k(
    const float* __restrict__ We1l, const float* __restrict__ be1l,
    const float* __restrict__ g1l, const float* __restrict__ bb1l,
    const float* __restrict__ We2l, const float* __restrict__ be2l,
    const float* __restrict__ WkEl, const float* __restrict__ bkl,
    const float* __restrict__ WmEl, const float* __restrict__ bml,
    float* __restrict__ ketab, float* __restrict__ metab)
{
  __shared__ float r_s[DD];
  __shared__ float e_s[DD];
  const int t = blockIdx.x, d = threadIdx.x;
  const float bnc = 0.99999500003749968752f;
  float pre = We1l[t * DD + d] + be1l[d];
  float bnv = pre * (g1l[d] * bnc) + bb1l[d];
  r_s[d] = fmaxf(bnv, 0.f);
  __syncthreads();
  float acc = 0.f;
  for (int c = 0; c < DD; ++c) acc += r_s[c] * We2l[c * DD + d];
  e_s[d] = acc + be2l[d];
  __syncthreads();
  float ka = 0.f, ma = 0.f;
  for (int c = 0; c < DD; ++c) {
    float ec = e_s[c];
    ka += ec * WkEl[c * DD + d];
    ma += ec * WmEl[c * DD + d];
  }
  ketab[t * DD + d] = ka + bkl[d];
  metab[t * DD + d] = ma + bml[d];
}

// ---------------- degree counts ----------------
__global__ void deg_k(const int* __restrict__ ei, int* __restrict__ cnt,
                      int* __restrict__ cnt_d)
{
  for (int e = blockIdx.x * blockDim.x + threadIdx.x; e < EE; e += gridDim.x * blockDim.x) {
    atomicAdd(&cnt[ei[e]], 1);        // src out-degree (real edges)
    atomicAdd(&cnt_d[ei[EE + e]], 1); // dst in-degree (real edges)
  }
}

// ---------------- exclusive scan over cnt_d (single block) ----------------
__global__ __launch_bounds__(256) void scan_k(const int* __restrict__ c,
                                              int* __restrict__ offs)
{
  __shared__ int part[257];
  const int tid = threadIdx.x;
  const int CH = (NN + 255) / 256;
  int a = tid * CH, b = a + CH; if (b > NN) b = NN;
  int s = 0;
  for (int i = a; i < b; ++i) s += c[i];
  part[tid] = s;
  __syncthreads();
  if (tid == 0) {
    int r = 0;
    for (int i = 0; i < 256; ++i) { int v = part[i]; part[i] = r; r += v; }
    part[256] = r;
  }
  __syncthreads();
  int r = part[tid];
  for (int i = a; i < b; ++i) { offs[i] = r; r += c[i]; }
  if (tid == 255) offs[NN] = part[256];
}

// ---------------- CSR fill (by dst) ----------------
__global__ void fill_k(const int* __restrict__ ei, const int* __restrict__ offs,
                       int* __restrict__ fc, int* __restrict__ eix)
{
  for (int e = blockIdx.x * blockDim.x + threadIdx.x; e < EE; e += gridDim.x * blockDim.x) {
    int d = ei[EE + e];
    int p = offs[d] + atomicAdd(&fc[d], 1);
    eix[p] = e;
  }
}

// ---------------- pass A: attention scores + segment max over src ----------
__global__ __launch_bounds__(256) void score_k(
    const float* __restrict__ Q, const float* __restrict__ Kn,
    const float* __restrict__ ketab, const int* __restrict__ ei,
    const int* __restrict__ et, float* __restrict__ sbuf,
    unsigned* __restrict__ smax)
{
  __shared__ float ke_s[NT * DD];
  for (int i = threadIdx.x; i < NT * DD; i += 256) ke_s[i] = ketab[i];
  __syncthreads();
  const int lane = threadIdx.x & 63, wave = threadIdx.x >> 6;
  const float4* Q4 = (const float4*)Q;
  const float4* K4 = (const float4*)Kn;
  for (int e = blockIdx.x * 4 + wave; e < ETOTAL; e += gridDim.x * 4) {
    int src, dst, t;
    if (e < EE) { src = ei[e]; dst = ei[EE + e]; t = et[e]; }
    else { src = dst = e - EE; t = NT - 1; }
    float4 q = Q4[src * 64 + lane];
    float4 k = K4[dst * 64 + lane];
    float4 ke = *(const float4*)(ke_s + t * DD + lane * 4);
    float p = q.x * (k.x + ke.x) + q.y * (k.y + ke.y) +
              q.z * (k.z + ke.z) + q.w * (k.w + ke.w);
    p += __shfl_xor(p, 8); p += __shfl_xor(p, 4);
    p += __shfl_xor(p, 2); p += __shfl_xor(p, 1);
    if ((lane & 15) == 0) {
      int h = lane >> 4;
      float s = p * 0.125f;            // / sqrt(64)
      sbuf[e * 4 + h] = s;
      atomicMax(smax + src * 4 + h, fenc(s));
    }
  }
}

// ---------------- pass B: exp(s - max) and segment sum over src ------------
__global__ void softmax_k(const int* __restrict__ ei, float* __restrict__ sbuf,
                          const unsigned* __restrict__ smax, float* __restrict__ den)
{
  for (int idx = blockIdx.x * blockDim.x + threadIdx.x; idx < ETOTAL * 4;
       idx += gridDim.x * blockDim.x) {
    int e = idx >> 2, h = idx & 3;
    int src = (e < EE) ? ei[e] : e - EE;
    float s = sbuf[idx];
    float ex = expf(s - fdec(smax[src * 4 + h]));
    sbuf[idx] = ex;
    atomicAdd(den + src * 4 + h, ex);
  }
}

// ---------------- pass C: atomic-free aggregation (wave per dst) -----------
__global__ __launch_bounds__(256) void aggr2_k(
    const float* __restrict__ Mn, const float* __restrict__ metab,
    const int* __restrict__ ei, const int* __restrict__ et,
    const float* __restrict__ sbuf, const float* __restrict__ den,
    const int* __restrict__ cnt, const int* __restrict__ offs,
    const int* __restrict__ eix, float* __restrict__ aggr)
{
  __shared__ float me_s[NT * DD];
  for (int i = threadIdx.x; i < NT * DD; i += 256) me_s[i] = metab[i];
  __syncthreads();
  const int lane = threadIdx.x & 63, wave = threadIdx.x >> 6;
  const int h = lane >> 4;
  const float4* M4 = (const float4*)Mn;
  int dst = blockIdx.x * 4 + wave;
  if (dst >= NN) return;
  float4 acc;
  {
    // self-loop (edge id EE+dst, type NT-1)
    float ex = sbuf[(EE + dst) * 4 + h];
    float dn = den[dst * 4 + h];
    float alpha = ex / (dn + 1e-16f) * (float)(cnt[dst] + 1);
    float4 m = M4[dst * 64 + lane];
    float4 me = *(const float4*)(me_s + (NT - 1) * DD + lane * 4);
    acc.x = (m.x + me.x) * alpha; acc.y = (m.y + me.y) * alpha;
    acc.z = (m.z + me.z) * alpha; acc.w = (m.w + me.w) * alpha;
  }
  int o1 = offs[dst + 1];
  for (int o = offs[dst]; o < o1; ++o) {
    int e = eix[o];
    int src = ei[e], t = et[e];
    float ex = sbuf[e * 4 + h];
    float dn = den[src * 4 + h];
    float alpha = ex / (dn + 1e-16f) * (float)(cnt[src] + 1);
    float4 m = M4[src * 64 + lane];
    float4 me = *(const float4*)(me_s + t * DD + lane * 4);
    acc.x += (m.x + me.x) * alpha; acc.y += (m.y + me.y) * alpha;
    acc.z += (m.z + me.z) * alpha; acc.w += (m.w + me.w) * alpha;
  }
  ((float4*)aggr)[dst * 64 + lane] = acc;
}

// ---------------- emissions: em = hidden @ Wt + bt  (256 -> 9) -------------
__global__ __launch_bounds__(256) void emis_k(
    const float* __restrict__ hidden, const float* __restrict__ Wt,
    const float* __restrict__ bt, float* __restrict__ em)
{
  __shared__ float wt_s[DD * NT];
  for (int i = threadIdx.x; i < DD * NT; i += 256) wt_s[i] = Wt[i];
  __syncthreads();
  const int lane = threadIdx.x & 63, wave = threadIdx.x >> 6;
  const float4* H4 = (const float4*)hidden;
  for (int n = blockIdx.x * 4 + wave; n < NN; n += gridDim.x * 4) {
    float4 h = H4[n * 64 + lane];
    const float* w0 = wt_s + (lane * 4) * NT;
    float p[NT];
#pragma unroll
    for (int t = 0; t < NT; ++t)
      p[t] = h.x * w0[t] + h.y * w0[NT + t] + h.z * w0[2 * NT + t] + h.w * w0[3 * NT + t];
#pragma unroll
    for (int m = 32; m >= 1; m >>= 1)
#pragma unroll
      for (int t = 0; t < NT; ++t) p[t] += __shfl_xor(p[t], m);
    if (lane == 0) {
#pragma unroll
      for (int t = 0; t < NT; ++t) em[n * NT + t] = p[t] + bt[t];
    }
  }
}

// ---------------- Viterbi decode (single block) ----------------------------
// Forward scan: wave0, lanes replicate states j=min(lane&15,8). Per-step
// recurrence pinned with inline asm: 9 grouped v_readlane (SGPR hazards
// covered by instruction spacing), 9 v_add (SGPR src0), exact v_max3 tree
// (9->3->1, max exactly associative -> bitwise identical to reference),
// + emission. Score rows stored stride-64; backpointers recomputed
// bitwise-exactly in the parallel backtrack (first-index tie rule).
__global__ __launch_bounds__(256) void viterbi_k(
    const float* __restrict__ em, const float* __restrict__ cstart,
    const float* __restrict__ cend, const float* __restrict__ ctrans,
    float* __restrict__ sv, int* __restrict__ outp)
{
  const int VCS = 512;
  const int NCH = (NN + VCS - 1) / VCS;
  __shared__ float embuf[2][VCS * NT + 32];   // +pad: compute reads off+2
  __shared__ float trT[NT * 16];              // trT[j*16+i] = trans[i][j]
  __shared__ float scf[NT];
  __shared__ unsigned char fmaps[256][NT];
  __shared__ unsigned char ends_s[256];
  __shared__ int last_s;
  const int tid = threadIdx.x, lane = tid & 63, wave = tid >> 6;
  const int jl = min(lane & 15, NT - 1);

  for (int i = tid; i < VCS * NT; i += 256) embuf[0][i] = em[i];
  if (tid < NT * NT) trT[(tid % NT) * 16 + (tid / NT)] = ctrans[tid];
  __syncthreads();

  float tcol[NT];   // tcol[i] = trans[i][jl]
  float s = 0.f;
  if (wave == 0) {
#pragma unroll
    for (int i = 0; i < NT; ++i) tcol[i] = ctrans[i * NT + jl];
    s = cstart[jl] + embuf[0][jl];
    sv[lane] = s;                 // row t=0, stride 64
  }

  for (int c = 0; c < NCH; ++c) {
    if (wave > 0) {
      if (c + 1 < NCH) {
        int base = (c + 1) * VCS * NT;
        int n2 = VCS * NT;
        if (base + n2 > NN * NT) n2 = NN * NT - base;
        for (int i = tid - 64; i < n2; i += 192) embuf[(c + 1) & 1][i] = em[base + i];
      }
    } else {
      const float* eb = embuf[c & 1];
      int tbeg = (c == 0) ? 1 : c * VCS;
      int tend = (c + 1) * VCS; if (tend > NN) tend = NN;
      int off = tbeg - c * VCS;
      float* svp = sv + (size_t)tbeg * 64 + lane;
      float e0 = eb[off * NT + jl];
      float e1 = eb[(off + 1) * NT + jl];
      for (int t = tbeg; t < tend; ++t, ++off) {
        float e2 = eb[(off + 2) * NT + jl];   // pad-safe
        float f0, f1, f2, f3, f4, f5, f6, f7, f8;       // SGPR broadcasts
        float c0, c1, c2, c3, c4, c5, c6, c7, c8;       // candidates
        asm volatile(
          "s_nop 1\n\t"
          "v_readlane_b32 %[f0], %[sv], 0\n\t"
          "v_readlane_b32 %[f1], %[sv], 1\n\t"
          "v_readlane_b32 %[f2], %[sv], 2\n\t"
          "v_readlane_b32 %[f3], %[sv], 3\n\t"
          "v_readlane_b32 %[f4], %[sv], 4\n\t"
          "v_readlane_b32 %[f5], %[sv], 5\n\t"
          "v_readlane_b32 %[f6], %[sv], 6\n\t"
          "v_readlane_b32 %[f7], %[sv], 7\n\t"
          "v_readlane_b32 %[f8], %[sv], 8\n\t"
          "v_add_f32 %[c0], %[f0], %[u0]\n\t"
          "v_add_f32 %[c1], %[f1], %[u1]\n\t"
          "v_add_f32 %[c2], %[f2], %[u2]\n\t"
          "v_add_f32 %[c3], %[f3], %[u3]\n\t"
          "v_add_f32 %[c4], %[f4], %[u4]\n\t"
          "v_add_f32 %[c5], %[f5], %[u5]\n\t"
          "v_add_f32 %[c6], %[f6], %[u6]\n\t"
          "v_add_f32 %[c7], %[f7], %[u7]\n\t"
          "v_add_f32 %[c8], %[f8], %[u8]\n\t"
          "v_max3_f32 %[c0], %[c0], %[c1], %[c2]\n\t"
          "v_max3_f32 %[c3], %[c3], %[c4], %[c5]\n\t"
          "v_max3_f32 %[c6], %[c6], %[c7], %[c8]\n\t"
          "v_max3_f32 %[c0], %[c0], %[c3], %[c6]\n\t"
          "v_add_f32 %[c0], %[c0], %[e]\n\t"
          : [f0]"=&s"(f0), [f1]"=&s"(f1), [f2]"=&s"(f2),
            [f3]"=&s"(f3), [f4]"=&s"(f4), [f5]"=&s"(f5),
            [f6]"=&s"(f6), [f7]"=&s"(f7), [f8]"=&s"(f8),
            [c0]"=&v"(c0), [c1]"=&v"(c1), [c2]"=&v"(c2),
            [c3]"=&v"(c3), [c4]"=&v"(c4), [c5]"=&v"(c5),
            [c6]"=&v"(c6), [c7]"=&v"(c7), [c8]"=&v"(c8)
          : [sv]"v"(s), [e]"v"(e0),
            [u0]"v"(tcol[0]), [u1]"v"(tcol[1]), [u2]"v"(tcol[2]),
            [u3]"v"(tcol[3]), [u4]"v"(tcol[4]), [u5]"v"(tcol[5]),
            [u6]"v"(tcol[6]), [u7]"v"(tcol[7]), [u8]"v"(tcol[8]));
        s = c0;
        *svp = s; svp += 64;
        e0 = e1; e1 = e2;
      }
    }
    __syncthreads();
  }

  if (wave == 0 && lane < NT) scf[lane] = s + cend[lane];
  __syncthreads();
  if (tid == 0) {
    float bv = scf[0]; int bi = 0;
    for (int j = 1; j < NT; ++j) if (scf[j] > bv) { bv = scf[j]; bi = j; }
    last_s = bi;
  }
  __syncthreads();

  // backtrack: per-range end->start maps via exact bp recomputation
  const int RL = 79;
  int a = 1 + tid * RL;
  int b = a + RL; if (b > NN) b = NN;
  bool active = (a < NN);
  if (active) {
    int x[NT];
#pragma unroll
    for (int j = 0; j < NT; ++j) x[j] = j;
    for (int t = b - 1; t >= a; --t) {
      const float* sp = sv + (size_t)(t - 1) * 64;
      float sr[NT];
#pragma unroll
      for (int i = 0; i < NT; ++i) sr[i] = sp[i];
#pragma unroll
      for (int j = 0; j < NT; ++j) {
        const float* tcx = trT + x[j] * 16;
        float bv = sr[0] + tcx[0]; int bi = 0;
#pragma unroll
        for (int i = 1; i < NT; ++i) {
          float cv = sr[i] + tcx[i];
          if (cv > bv) { bv = cv; bi = i; }
        }
        x[j] = bi;
      }
    }
#pragma unroll
    for (int j = 0; j < NT; ++j) fmaps[tid][j] = (unsigned char)x[j];
  }
  __syncthreads();
  if (tid == 0) {
    int x = last_s;
    for (int k = 255; k >= 0; --k) {
      ends_s[k] = (unsigned char)x;
      int ak = 1 + k * RL;
      if (ak < NN) x = fmaps[k][x];
    }
  }
  __syncthreads();
  if (active) {
    int x = ends_s[tid];
    outp[b - 1] = x;
    for (int t = b - 1; t >= a; --t) {
      const float* sp = sv + (size_t)(t - 1) * 64;
      const float* tcx = trT + x * 16;
      float bv = sp[0] + tcx[0]; int bi = 0;
#pragma unroll
      for (int i = 1; i < NT; ++i) {
        float cv = sp[i] + tcx[i];
        if (cv > bv) { bv = cv; bi = i; }
      }
      x = bi;
      outp[t - 1] = x;
    }
  }
}

// ---------------------------------------------------------------------------
extern "C" void kernel_launch(void* const* d_in, const int* in_sizes, int n_in,
                              void* d_out, int out_size, void* d_ws, size_t ws_size,
                              hipStream_t stream)
{
  const float* node_emb = (const float*)d_in[0];
  const int* edge_index = (const int*)d_in[1];
  const int* edge_type = (const int*)d_in[2];
  // d_in[3] = tag_gt (unused by reference)
  const float* W_lm2gnn = (const float*)d_in[4];
  const float* b_lm2gnn = (const float*)d_in[5];
  const float* We1 = (const float*)d_in[6];
  const float* be1 = (const float*)d_in[7];
  const float* g1 = (const float*)d_in[8];
  const float* bb1 = (const float*)d_in[9];
  const float* We2 = (const float*)d_in[10];
  const float* be2 = (const float*)d_in[11];
  const float* Wq = (const float*)d_in[12];
  const float* bq = (const float*)d_in[13];
  const float* Wk = (const float*)d_in[14];
  const float* bk = (const float*)d_in[15];
  const float* Wm = (const float*)d_in[16];
  const float* bm = (const float*)d_in[17];
  const float* Wp1 = (const float*)d_in[18];
  const float* bp1 = (const float*)d_in[19];
  const float* g2 = (const float*)d_in[20];
  const float* bb2 = (const float*)d_in[21];
  const float* Wp2 = (const float*)d_in[22];
  const float* bp2 = (const float*)d_in[23];
  const float* Wo = (const float*)d_in[24];
  const float* bo = (const float*)d_in[25];
  const float* Wc = (const float*)d_in[26];
  const float* bc = (const float*)d_in[27];
  const float* Wt = (const float*)d_in[28];
  const float* bt = (const float*)d_in[29];
  const float* cstart = (const float*)d_in[30];
  const float* cend = (const float*)d_in[31];
  const float* ctrans = (const float*)d_in[32];

  // Workspace layout: 4 big node buffers + small region.
  const size_t NB = (size_t)NN * DD * sizeof(float); // 20,480,000
  char* w = (char*)d_ws;
  float* H0 = (float*)(w + 0 * NB);
  float* Xb = (float*)(w + 1 * NB);
  float* Qb = (float*)(w + 2 * NB);   // Q, then M, then Xl, then hidden
  float* Kb = (float*)(w + 3 * NB);   // K, then aggr, then H0@Wo tmp
  char* sm = w + 4 * NB;
  size_t smo = 0;
  auto alloc = [&](size_t bytes) { char* p = sm + smo; smo += (bytes + 255) & ~255ull; return p; };
  float* sbuf = (float*)alloc((size_t)ETOTAL * 4 * 4);
  unsigned* smax = (unsigned*)alloc((size_t)NN * 4 * 4);   // contiguous with den
  float* den = (float*)alloc((size_t)NN * 4 * 4);
  int* cnt = (int*)alloc((size_t)NN * 4);                  // cnt..fc zeroed together
  int* cnt_d = (int*)alloc((size_t)NN * 4);
  int* offs = (int*)alloc((size_t)(NN + 1) * 4);
  int* fc = (int*)alloc((size_t)NN * 4);
  int* eix = (int*)alloc((size_t)EE * 4);
  float* ketab = (float*)alloc((size_t)NT * DD * 4);
  float* metab = (float*)alloc((size_t)NT * DD * 4);
  float* em = (float*)alloc((size_t)NN * NT * 4);
  float* sv = (float*)alloc(((size_t)NN * 64 + 64) * 4);   // stride-64 score rows
  const size_t needed = 4 * NB + smo;
  if (ws_size < needed) return;  // fail visibly rather than corrupt

  dim3 gg(DD / 64, (NN + 63) / 64);

  // degree counts + dst-CSR (edge structure constant across layers)
  hipMemsetAsync(cnt, 0, (size_t)((char*)eix - (char*)cnt), stream); // cnt,cnt_d,offs,fc
  deg_k<<<1024, 256, 0, stream>>>(edge_index, cnt, cnt_d);
  scan_k<<<1, 256, 0, stream>>>(cnt_d, offs);
  fill_k<<<1024, 256, 0, stream>>>(edge_index, offs, fc, eix);

  // H0 = gelu(node_emb @ W_lm2gnn + b)
  gemm_k<<<gg, 256, 0, stream>>>(node_emb, W_lm2gnn, b_lm2gnn, nullptr, nullptr,
                                 nullptr, H0, NN, DIN, DD, 1);

  const float* Xcur = H0;
  for (int l = 0; l < 3; ++l) {
    edge_tables_k<<<NT, 256, 0, stream>>>(
        We1 + (size_t)l * NT * DD, be1 + l * DD, g1 + l * DD, bb1 + l * DD,
        We2 + (size_t)l * DD * DD, be2 + l * DD,
        Wk + (size_t)l * 2 * DD * DD + DD * DD, bk + l * DD,
        Wm + (size_t)l * 2 * DD * DD + DD * DD, bm + l * DD, ketab, metab);

    gemm_k<<<gg, 256, 0, stream>>>(Xcur, Wq + (size_t)l * DD * DD, bq + l * DD,
                                   nullptr, nullptr, nullptr, Qb, NN, DD, DD, 0);
    gemm_k<<<gg, 256, 0, stream>>>(Xcur, Wk + (size_t)l * 2 * DD * DD, nullptr,
                                   nullptr, nullptr, nullptr, Kb, NN, DD, DD, 0);

    hipMemsetAsync(smax, 0, (size_t)NN * 4 * 4 * 2, stream);  // smax + den
    score_k<<<2048, 256, 0, stream>>>(Qb, Kb, ketab, edge_index, edge_type, sbuf, smax);
    softmax_k<<<2048, 256, 0, stream>>>(edge_index, sbuf, smax, den);

    // M projection into Qb (Q dead after score_k)
    gemm_k<<<gg, 256, 0, stream>>>(Xcur, Wm + (size_t)l * 2 * DD * DD, nullptr,
                                   nullptr, nullptr, nullptr, Qb, NN, DD, DD, 0);
    // aggregate into Kb (K dead after score_k)
    aggr2_k<<<(NN + 3) / 4, 256, 0, stream>>>(Qb, metab, edge_index, edge_type,
                                              sbuf, den, cnt, offs, eix, Kb);

    // Xl = relu(bn(aggr@Wp1 + bp1)); X = gelu(Xl@Wp2 + bp2)
    gemm_k<<<gg, 256, 0, stream>>>(Kb, Wp1 + (size_t)l * DD * DD, bp1 + l * DD,
                                   nullptr, g2 + l * DD, bb2 + l * DD, Qb, NN, DD, DD, 2);
    gemm_k<<<gg, 256, 0, stream>>>(Qb, Wp2 + (size_t)l * DD * DD, bp2 + l * DD,
                                   nullptr, nullptr, nullptr, Xb, NN, DD, DD, 1);
    Xcur = Xb;
  }

  // hidden = gelu(H0@Wo + bo + X@Wc + bc)
  gemm_k<<<gg, 256, 0, stream>>>(H0, Wo, bo, nullptr, nullptr, nullptr, Kb, NN, DD, DD, 0);
  gemm_k<<<gg, 256, 0, stream>>>(Xb, Wc, bc, Kb, nullptr, nullptr, Qb, NN, DD, DD, 1);

  emis_k<<<1250, 256, 0, stream>>>(Qb, Wt, bt, em);
  viterbi_k<<<1, 256, 0, stream>>>(em, cstart, cend, ctrans, sv, (int*)d_out);
}

// Round 9
// 3084.520 us; speedup vs baseline: 1.0913x; 1.0913x over previous
//
#include <hip/hip_runtime.h>

// Problem constants (fixed by the reference)
#define NN 20000      // nodes
#define EE 240000     // real edges
#define ETOTAL 260000 // edges + self loops
#define DIN 768
#define DD 256
#define NT 9          // tags
// heads = 4, DH = 64

__device__ __forceinline__ unsigned fenc(float x) {
  unsigned u = __float_as_uint(x);
  return (u & 0x80000000u) ? ~u : (u | 0x80000000u);
}
__device__ __forceinline__ float fdec(unsigned e) {
  unsigned u = (e & 0x80000000u) ? (e ^ 0x80000000u) : ~e;
  return __uint_as_float(u);
}
__device__ __forceinline__ float gelu_f(float x) {
  return 0.5f * x * (1.0f + erff(x * 0.70710678118654752440f));
}

// One Viterbi recurrence step (R8 asm block, bitwise-exact): 9 grouped
// v_readlane (hazards covered by spacing), 9 v_add, exact v_max3 tree
// (9->3->1), + emission. Updates s, stores score row (stride 64).
#define VSTEP(EIN) do {                                                   \
  float f0, f1, f2, f3, f4, f5, f6, f7, f8;                               \
  float q0, q1, q2, q3, q4, q5, q6, q7, q8;                               \
  asm volatile(                                                           \
    "s_nop 1\n\t"                                                         \
    "v_readlane_b32 %[f0], %[sv], 0\n\t"                                  \
    "v_readlane_b32 %[f1], %[sv], 1\n\t"                                  \
    "v_readlane_b32 %[f2], %[sv], 2\n\t"                                  \
    "v_readlane_b32 %[f3], %[sv], 3\n\t"                                  \
    "v_readlane_b32 %[f4], %[sv], 4\n\t"                                  \
    "v_readlane_b32 %[f5], %[sv], 5\n\t"                                  \
    "v_readlane_b32 %[f6], %[sv], 6\n\t"                                  \
    "v_readlane_b32 %[f7], %[sv], 7\n\t"                                  \
    "v_readlane_b32 %[f8], %[sv], 8\n\t"                                  \
    "v_add_f32 %[q0], %[f0], %[u0]\n\t"                                   \
    "v_add_f32 %[q1], %[f1], %[u1]\n\t"                                   \
    "v_add_f32 %[q2], %[f2], %[u2]\n\t"                                   \
    "v_add_f32 %[q3], %[f3], %[u3]\n\t"                                   \
    "v_add_f32 %[q4], %[f4], %[u4]\n\t"                                   \
    "v_add_f32 %[q5], %[f5], %[u5]\n\t"                                   \
    "v_add_f32 %[q6], %[f6], %[u6]\n\t"                                   \
    "v_add_f32 %[q7], %[f7], %[u7]\n\t"                                   \
    "v_add_f32 %[q8], %[f8], %[u8]\n\t"                                   \
    "v_max3_f32 %[q0], %[q0], %[q1], %[q2]\n\t"                           \
    "v_max3_f32 %[q3], %[q3], %[q4], %[q5]\n\t"                           \
    "v_max3_f32 %[q6], %[q6], %[q7], %[q8]\n\t"                           \
    "v_max3_f32 %[q0], %[q0], %[q3], %[q6]\n\t"                           \
    "v_add_f32 %[q0], %[q0], %[e]\n\t"                                    \
    : [f0]"=&s"(f0), [f1]"=&s"(f1), [f2]"=&s"(f2),                        \
      [f3]"=&s"(f3), [f4]"=&s"(f4), [f5]"=&s"(f5),                        \
      [f6]"=&s"(f6), [f7]"=&s"(f7), [f8]"=&s"(f8),                        \
      [q0]"=&v"(q0), [q1]"=&v"(q1), [q2]"=&v"(q2),                        \
      [q3]"=&v"(q3), [q4]"=&v"(q4), [q5]"=&v"(q5),                        \
      [q6]"=&v"(q6), [q7]"=&v"(q7), [q8]"=&v"(q8)                         \
    : [sv]"v"(s), [e]"v"(EIN),                                            \
      [u0]"v"(tcol[0]), [u1]"v"(tcol[1]), [u2]"v"(tcol[2]),               \
      [u3]"v"(tcol[3]), [u4]"v"(tcol[4]), [u5]"v"(tcol[5]),               \
      [u6]"v"(tcol[6]), [u7]"v"(tcol[7]), [u8]"v"(tcol[8]));              \
  s = q0;                                                                 \
  *svp = s; svp += 64;                                                    \
} while (0)

// ---------------- GEMM: C = act(A@B + bias [+ addc]) ----------------
// A: MxK row-major, B: KxN row-major, C: MxN. Requires N%64==0, K%32==0.
// act: 0 = none, 1 = gelu, 2 = bn(g,b) then relu
// 64x64 tile, 4x4/thread (measured best of {64x64, 128x64} on this shape).
__global__ __launch_bounds__(256) void gemm_k(
    const float* __restrict__ A, const float* __restrict__ B,
    const float* __restrict__ bias, const float* __restrict__ addc,
    const float* __restrict__ bng, const float* __restrict__ bnb,
    float* __restrict__ C, int M, int K, int N, int act)
{
  __shared__ float As[32][64];   // transposed A tile: As[k][m]
  __shared__ float Bs[32][64];   // Bs[k][n]
  const int tid = threadIdx.x;
  const int tx = tid & 15, ty = tid >> 4;
  const int m0 = blockIdx.y * 64, n0 = blockIdx.x * 64;
  float acc[4][4];
#pragma unroll
  for (int i = 0; i < 4; ++i)
#pragma unroll
    for (int j = 0; j < 4; ++j) acc[i][j] = 0.f;

  for (int kk = 0; kk < K; kk += 32) {
#pragma unroll
    for (int L = tid; L < 512; L += 256) {   // A tile: 64 rows x 8 float4
      int r = L >> 3, c4 = L & 7;
      int gm = m0 + r;
      float4 v = make_float4(0.f, 0.f, 0.f, 0.f);
      if (gm < M) v = *(const float4*)(A + (size_t)gm * K + kk + c4 * 4);
      As[c4 * 4 + 0][r] = v.x; As[c4 * 4 + 1][r] = v.y;
      As[c4 * 4 + 2][r] = v.z; As[c4 * 4 + 3][r] = v.w;
    }
#pragma unroll
    for (int L = tid; L < 512; L += 256) {   // B tile: 32 rows x 16 float4
      int r = L >> 4, c4 = L & 15;
      *(float4*)&Bs[r][c4 * 4] = *(const float4*)(B + (size_t)(kk + r) * N + n0 + c4 * 4);
    }
    __syncthreads();
#pragma unroll
    for (int k = 0; k < 32; ++k) {
      float a[4], b[4];
      *(float4*)a = *(const float4*)&As[k][ty * 4];
      *(float4*)b = *(const float4*)&Bs[k][tx * 4];
#pragma unroll
      for (int i = 0; i < 4; ++i)
#pragma unroll
        for (int j = 0; j < 4; ++j) acc[i][j] += a[i] * b[j];
    }
    __syncthreads();
  }
  const float bnc = 0.99999500003749968752f;  // 1/sqrt(1+1e-5)
#pragma unroll
  for (int i = 0; i < 4; ++i) {
    int gm = m0 + ty * 4 + i;
    if (gm >= M) continue;
    float o[4];
#pragma unroll
    for (int j = 0; j < 4; ++j) {
      int n = n0 + tx * 4 + j;
      float x = acc[i][j];
      if (bias) x += bias[n];
      if (addc) x += addc[(size_t)gm * N + n];
      if (act == 1) x = gelu_f(x);
      else if (act == 2) { x = x * (bng[n] * bnc) + bnb[n]; x = fmaxf(x, 0.f); }
      o[j] = x;
    }
    *(float4*)(C + (size_t)gm * N + n0 + tx * 4) = *(const float4*)o;
  }
}

// ---------------- per-layer edge-type tables (9 types) ----------------
__global__ __launch_bounds__(256) void edge_tables_k(
    const float* __restrict__ We1l, const float* __restrict__ be1l,
    const float* __restrict__ g1l, const float* __restrict__ bb1l,
    const float* __restrict__ We2l, const float* __restrict__ be2l,
    const float* __restrict__ WkEl, const float* __restrict__ bkl,
    const float* __restrict__ WmEl, const float* __restrict__ bml,
    float* __restrict__ ketab, float* __restrict__ metab)
{
  __shared__ float r_s[DD];
  __shared__ float e_s[DD];
  const int t = blockIdx.x, d = threadIdx.x;
  const float bnc = 0.99999500003749968752f;
  float pre = We1l[t * DD + d] + be1l[d];
  float bnv = pre * (g1l[d] * bnc) + bb1l[d];
  r_s[d] = fmaxf(bnv, 0.f);
  __syncthreads();
  float acc = 0.f;
  for (int c = 0; c < DD; ++c) acc += r_s[c] * We2l[c * DD + d];
  e_s[d] = acc + be2l[d];
  __syncthreads();
  float ka = 0.f, ma = 0.f;
  for (int c = 0; c < DD; ++c) {
    float ec = e_s[c];
    ka += ec * WkEl[c * DD + d];
    ma += ec * WmEl[c * DD + d];
  }
  ketab[t * DD + d] = ka + bkl[d];
  metab[t * DD + d] = ma + bml[d];
}

// ---------------- degree counts ----------------
__global__ void deg_k(const int* __restrict__ ei, int* __restrict__ cnt,
                      int* __restrict__ cnt_d)
{
  for (int e = blockIdx.x * blockDim.x + threadIdx.x; e < EE; e += gridDim.x * blockDim.x) {
    atomicAdd(&cnt[ei[e]], 1);        // src out-degree (real edges)
    atomicAdd(&cnt_d[ei[EE + e]], 1); // dst in-degree (real edges)
  }
}

// ---------------- exclusive scan over cnt_d (single block) ----------------
__global__ __launch_bounds__(256) void scan_k(const int* __restrict__ c,
                                              int* __restrict__ offs)
{
  __shared__ int part[257];
  const int tid = threadIdx.x;
  const int CH = (NN + 255) / 256;
  int a = tid * CH, b = a + CH; if (b > NN) b = NN;
  int s = 0;
  for (int i = a; i < b; ++i) s += c[i];
  part[tid] = s;
  __syncthreads();
  if (tid == 0) {
    int r = 0;
    for (int i = 0; i < 256; ++i) { int v = part[i]; part[i] = r; r += v; }
    part[256] = r;
  }
  __syncthreads();
  int r = part[tid];
  for (int i = a; i < b; ++i) { offs[i] = r; r += c[i]; }
  if (tid == 255) offs[NN] = part[256];
}

// ---------------- CSR fill (by dst) ----------------
__global__ void fill_k(const int* __restrict__ ei, const int* __restrict__ offs,
                       int* __restrict__ fc, int* __restrict__ eix)
{
  for (int e = blockIdx.x * blockDim.x + threadIdx.x; e < EE; e += gridDim.x * blockDim.x) {
    int d = ei[EE + e];
    int p = offs[d] + atomicAdd(&fc[d], 1);
    eix[p] = e;
  }
}

// ---------------- pass A: attention scores + segment max over src ----------
__global__ __launch_bounds__(256) void score_k(
    const float* __restrict__ Q, const float* __restrict__ Kn,
    const float* __restrict__ ketab, const int* __restrict__ ei,
    const int* __restrict__ et, float* __restrict__ sbuf,
    unsigned* __restrict__ smax)
{
  __shared__ float ke_s[NT * DD];
  for (int i = threadIdx.x; i < NT * DD; i += 256) ke_s[i] = ketab[i];
  __syncthreads();
  const int lane = threadIdx.x & 63, wave = threadIdx.x >> 6;
  const float4* Q4 = (const float4*)Q;
  const float4* K4 = (const float4*)Kn;
  for (int e = blockIdx.x * 4 + wave; e < ETOTAL; e += gridDim.x * 4) {
    int src, dst, t;
    if (e < EE) { src = ei[e]; dst = ei[EE + e]; t = et[e]; }
    else { src = dst = e - EE; t = NT - 1; }
    float4 q = Q4[src * 64 + lane];
    float4 k = K4[dst * 64 + lane];
    float4 ke = *(const float4*)(ke_s + t * DD + lane * 4);
    float p = q.x * (k.x + ke.x) + q.y * (k.y + ke.y) +
              q.z * (k.z + ke.z) + q.w * (k.w + ke.w);
    p += __shfl_xor(p, 8); p += __shfl_xor(p, 4);
    p += __shfl_xor(p, 2); p += __shfl_xor(p, 1);
    if ((lane & 15) == 0) {
      int h = lane >> 4;
      float s = p * 0.125f;            // / sqrt(64)
      sbuf[e * 4 + h] = s;
      atomicMax(smax + src * 4 + h, fenc(s));
    }
  }
}

// ---------------- pass B: exp(s - max) and segment sum over src ------------
__global__ void softmax_k(const int* __restrict__ ei, float* __restrict__ sbuf,
                          const unsigned* __restrict__ smax, float* __restrict__ den)
{
  for (int idx = blockIdx.x * blockDim.x + threadIdx.x; idx < ETOTAL * 4;
       idx += gridDim.x * blockDim.x) {
    int e = idx >> 2, h = idx & 3;
    int src = (e < EE) ? ei[e] : e - EE;
    float s = sbuf[idx];
    float ex = expf(s - fdec(smax[src * 4 + h]));
    sbuf[idx] = ex;
    atomicAdd(den + src * 4 + h, ex);
  }
}

// ---------------- pass C: atomic-free aggregation (wave per dst) -----------
__global__ __launch_bounds__(256) void aggr2_k(
    const float* __restrict__ Mn, const float* __restrict__ metab,
    const int* __restrict__ ei, const int* __restrict__ et,
    const float* __restrict__ sbuf, const float* __restrict__ den,
    const int* __restrict__ cnt, const int* __restrict__ offs,
    const int* __restrict__ eix, float* __restrict__ aggr)
{
  __shared__ float me_s[NT * DD];
  for (int i = threadIdx.x; i < NT * DD; i += 256) me_s[i] = metab[i];
  __syncthreads();
  const int lane = threadIdx.x & 63, wave = threadIdx.x >> 6;
  const int h = lane >> 4;
  const float4* M4 = (const float4*)Mn;
  int dst = blockIdx.x * 4 + wave;
  if (dst >= NN) return;
  float4 acc;
  {
    // self-loop (edge id EE+dst, type NT-1)
    float ex = sbuf[(EE + dst) * 4 + h];
    float dn = den[dst * 4 + h];
    float alpha = ex / (dn + 1e-16f) * (float)(cnt[dst] + 1);
    float4 m = M4[dst * 64 + lane];
    float4 me = *(const float4*)(me_s + (NT - 1) * DD + lane * 4);
    acc.x = (m.x + me.x) * alpha; acc.y = (m.y + me.y) * alpha;
    acc.z = (m.z + me.z) * alpha; acc.w = (m.w + me.w) * alpha;
  }
  int o1 = offs[dst + 1];
  for (int o = offs[dst]; o < o1; ++o) {
    int e = eix[o];
    int src = ei[e], t = et[e];
    float ex = sbuf[e * 4 + h];
    float dn = den[src * 4 + h];
    float alpha = ex / (dn + 1e-16f) * (float)(cnt[src] + 1);
    float4 m = M4[src * 64 + lane];
    float4 me = *(const float4*)(me_s + t * DD + lane * 4);
    acc.x += (m.x + me.x) * alpha; acc.y += (m.y + me.y) * alpha;
    acc.z += (m.z + me.z) * alpha; acc.w += (m.w + me.w) * alpha;
  }
  ((float4*)aggr)[dst * 64 + lane] = acc;
}

// ---------------- emissions: em = hidden @ Wt + bt  (256 -> 9) -------------
__global__ __launch_bounds__(256) void emis_k(
    const float* __restrict__ hidden, const float* __restrict__ Wt,
    const float* __restrict__ bt, float* __restrict__ em)
{
  __shared__ float wt_s[DD * NT];
  for (int i = threadIdx.x; i < DD * NT; i += 256) wt_s[i] = Wt[i];
  __syncthreads();
  const int lane = threadIdx.x & 63, wave = threadIdx.x >> 6;
  const float4* H4 = (const float4*)hidden;
  for (int n = blockIdx.x * 4 + wave; n < NN; n += gridDim.x * 4) {
    float4 h = H4[n * 64 + lane];
    const float* w0 = wt_s + (lane * 4) * NT;
    float p[NT];
#pragma unroll
    for (int t = 0; t < NT; ++t)
      p[t] = h.x * w0[t] + h.y * w0[NT + t] + h.z * w0[2 * NT + t] + h.w * w0[3 * NT + t];
#pragma unroll
    for (int m = 32; m >= 1; m >>= 1)
#pragma unroll
      for (int t = 0; t < NT; ++t) p[t] += __shfl_xor(p[t], m);
    if (lane == 0) {
#pragma unroll
      for (int t = 0; t < NT; ++t) em[n * NT + t] = p[t] + bt[t];
    }
  }
}

// ---------------- Viterbi decode (single block) ----------------------------
// Forward scan: wave0, lanes replicate states j=min(lane&15,8). Recurrence =
// R8 asm block (readlane + add + exact max3 tree -> bitwise identical).
// This round: emission LDS reads batched 4-at-a-time and issued 8 steps
// ahead (2-block register rotation) so the ~120cy ds_read latency is off the
// critical chain. Score rows stored stride-64; backpointers recomputed
// bitwise-exactly in the parallel backtrack (first-index tie rule).
__global__ __launch_bounds__(256) void viterbi_k(
    const float* __restrict__ em, const float* __restrict__ cstart,
    const float* __restrict__ cend, const float* __restrict__ ctrans,
    float* __restrict__ sv, int* __restrict__ outp)
{
  const int VCS = 512;
  const int NCH = (NN + VCS - 1) / VCS;
  __shared__ float embuf[2][VCS * NT + 32];
  __shared__ float trT[NT * 16];              // trT[j*16+i] = trans[i][j]
  __shared__ float scf[NT];
  __shared__ unsigned char fmaps[256][NT];
  __shared__ unsigned char ends_s[256];
  __shared__ int last_s;
  const int tid = threadIdx.x, lane = tid & 63, wave = tid >> 6;
  const int jl = min(lane & 15, NT - 1);

  for (int i = tid; i < VCS * NT; i += 256) embuf[0][i] = em[i];
  if (tid < NT * NT) trT[(tid % NT) * 16 + (tid / NT)] = ctrans[tid];
  __syncthreads();

  float tcol[NT];   // tcol[i] = trans[i][jl]
  float s = 0.f;
  if (wave == 0) {
#pragma unroll
    for (int i = 0; i < NT; ++i) tcol[i] = ctrans[i * NT + jl];
    s = cstart[jl] + embuf[0][jl];
    sv[lane] = s;                 // row t=0, stride 64
  }

  for (int c = 0; c < NCH; ++c) {
    if (wave > 0) {
      if (c + 1 < NCH) {
        int base = (c + 1) * VCS * NT;
        int n2 = VCS * NT;
        if (base + n2 > NN * NT) n2 = NN * NT - base;
        for (int i = tid - 64; i < n2; i += 192) embuf[(c + 1) & 1][i] = em[base + i];
      }
    } else {
      const float* eb = embuf[c & 1];
      int tbeg = (c == 0) ? 1 : c * VCS;
      int tend = (c + 1) * VCS; if (tend > NN) tend = NN;
      int off = tbeg - c * VCS;
      int nsteps = tend - tbeg;
      float* svp = sv + (size_t)tbeg * 64 + lane;
      int i = 0;
      if (nsteps >= 12) {
        // software pipeline: a* = steps i..i+3, b* = steps i+4..i+7
        float a0 = eb[(off + 0) * NT + jl], a1 = eb[(off + 1) * NT + jl];
        float a2 = eb[(off + 2) * NT + jl], a3 = eb[(off + 3) * NT + jl];
        float b0 = eb[(off + 4) * NT + jl], b1 = eb[(off + 5) * NT + jl];
        float b2 = eb[(off + 6) * NT + jl], b3 = eb[(off + 7) * NT + jl];
        int nblk = (nsteps - 8) / 4;
        for (int bk = 0; bk < nblk; ++bk) {
          int lo = off + 8 + bk * 4;           // lo+3 <= off+nsteps-1: in-range
          float n0 = eb[(lo + 0) * NT + jl];
          float n1 = eb[(lo + 1) * NT + jl];
          float n2v = eb[(lo + 2) * NT + jl];
          float n3 = eb[(lo + 3) * NT + jl];
          VSTEP(a0); VSTEP(a1); VSTEP(a2); VSTEP(a3);
          a0 = b0; a1 = b1; a2 = b2; a3 = b3;
          b0 = n0; b1 = n1; b2 = n2v; b3 = n3;
        }
        i = nblk * 4;
        // drain the 8 pipelined emissions (rem = nsteps - i is in [8,11])
        VSTEP(a0); VSTEP(a1); VSTEP(a2); VSTEP(a3);
        VSTEP(b0); VSTEP(b1); VSTEP(b2); VSTEP(b3);
        i += 8;
      }
      for (; i < nsteps; ++i) {                // <=3 scalar tail steps
        float e0 = eb[(off + i) * NT + jl];
        VSTEP(e0);
      }
    }
    __syncthreads();
  }

  if (wave == 0 && lane < NT) scf[lane] = s + cend[lane];
  __syncthreads();
  if (tid == 0) {
    float bv = scf[0]; int bi = 0;
    for (int j = 1; j < NT; ++j) if (scf[j] > bv) { bv = scf[j]; bi = j; }
    last_s = bi;
  }
  __syncthreads();

  // backtrack: per-range end->start maps via exact bp recomputation
  const int RL = 79;
  int a = 1 + tid * RL;
  int b = a + RL; if (b > NN) b = NN;
  bool active = (a < NN);
  if (active) {
    int x[NT];
#pragma unroll
    for (int j = 0; j < NT; ++j) x[j] = j;
    for (int t = b - 1; t >= a; --t) {
      const float* sp = sv + (size_t)(t - 1) * 64;
      float sr[NT];
#pragma unroll
      for (int i = 0; i < NT; ++i) sr[i] = sp[i];
#pragma unroll
      for (int j = 0; j < NT; ++j) {
        const float* tcx = trT + x[j] * 16;
        float bv = sr[0] + tcx[0]; int bi = 0;
#pragma unroll
        for (int i = 1; i < NT; ++i) {
          float cv = sr[i] + tcx[i];
          if (cv > bv) { bv = cv; bi = i; }
        }
        x[j] = bi;
      }
    }
#pragma unroll
    for (int j = 0; j < NT; ++j) fmaps[tid][j] = (unsigned char)x[j];
  }
  __syncthreads();
  if (tid == 0) {
    int x = last_s;
    for (int k = 255; k >= 0; --k) {
      ends_s[k] = (unsigned char)x;
      int ak = 1 + k * RL;
      if (ak < NN) x = fmaps[k][x];
    }
  }
  __syncthreads();
  if (active) {
    int x = ends_s[tid];
    outp[b - 1] = x;
    for (int t = b - 1; t >= a; --t) {
      const float* sp = sv + (size_t)(t - 1) * 64;
      const float* tcx = trT + x * 16;
      float bv = sp[0] + tcx[0]; int bi = 0;
#pragma unroll
      for (int i = 1; i < NT; ++i) {
        float cv = sp[i] + tcx[i];
        if (cv > bv) { bv = cv; bi = i; }
      }
      x = bi;
      outp[t - 1] = x;
    }
  }
}

// ---------------------------------------------------------------------------
extern "C" void kernel_launch(void* const* d_in, const int* in_sizes, int n_in,
                              void* d_out, int out_size, void* d_ws, size_t ws_size,
                              hipStream_t stream)
{
  const float* node_emb = (const float*)d_in[0];
  const int* edge_index = (const int*)d_in[1];
  const int* edge_type = (const int*)d_in[2];
  // d_in[3] = tag_gt (unused by reference)
  const float* W_lm2gnn = (const float*)d_in[4];
  const float* b_lm2gnn = (const float*)d_in[5];
  const float* We1 = (const float*)d_in[6];
  const float* be1 = (const float*)d_in[7];
  const float* g1 = (const float*)d_in[8];
  const float* bb1 = (const float*)d_in[9];
  const float* We2 = (const float*)d_in[10];
  const float* be2 = (const float*)d_in[11];
  const float* Wq = (const float*)d_in[12];
  const float* bq = (const float*)d_in[13];
  const float* Wk = (const float*)d_in[14];
  const float* bk = (const float*)d_in[15];
  const float* Wm = (const float*)d_in[16];
  const float* bm = (const float*)d_in[17];
  const float* Wp1 = (const float*)d_in[18];
  const float* bp1 = (const float*)d_in[19];
  const float* g2 = (const float*)d_in[20];
  const float* bb2 = (const float*)d_in[21];
  const float* Wp2 = (const float*)d_in[22];
  const float* bp2 = (const float*)d_in[23];
  const float* Wo = (const float*)d_in[24];
  const float* bo = (const float*)d_in[25];
  const float* Wc = (const float*)d_in[26];
  const float* bc = (const float*)d_in[27];
  const float* Wt = (const float*)d_in[28];
  const float* bt = (const float*)d_in[29];
  const float* cstart = (const float*)d_in[30];
  const float* cend = (const float*)d_in[31];
  const float* ctrans = (const float*)d_in[32];

  // Workspace layout: 4 big node buffers + small region.
  const size_t NB = (size_t)NN * DD * sizeof(float); // 20,480,000
  char* w = (char*)d_ws;
  float* H0 = (float*)(w + 0 * NB);
  float* Xb = (float*)(w + 1 * NB);
  float* Qb = (float*)(w + 2 * NB);   // Q, then M, then Xl, then hidden
  float* Kb = (float*)(w + 3 * NB);   // K, then aggr, then H0@Wo tmp
  char* sm = w + 4 * NB;
  size_t smo = 0;
  auto alloc = [&](size_t bytes) { char* p = sm + smo; smo += (bytes + 255) & ~255ull; return p; };
  float* sbuf = (float*)alloc((size_t)ETOTAL * 4 * 4);
  unsigned* smax = (unsigned*)alloc((size_t)NN * 4 * 4);   // contiguous with den
  float* den = (float*)alloc((size_t)NN * 4 * 4);
  int* cnt = (int*)alloc((size_t)NN * 4);                  // cnt..fc zeroed together
  int* cnt_d = (int*)alloc((size_t)NN * 4);
  int* offs = (int*)alloc((size_t)(NN + 1) * 4);
  int* fc = (int*)alloc((size_t)NN * 4);
  int* eix = (int*)alloc((size_t)EE * 4);
  float* ketab = (float*)alloc((size_t)NT * DD * 4);
  float* metab = (float*)alloc((size_t)NT * DD * 4);
  float* em = (float*)alloc((size_t)NN * NT * 4);
  float* sv = (float*)alloc(((size_t)NN * 64 + 64) * 4);   // stride-64 score rows
  const size_t needed = 4 * NB + smo;
  if (ws_size < needed) return;  // fail visibly rather than corrupt

  dim3 gg(DD / 64, (NN + 63) / 64);

  // degree counts + dst-CSR (edge structure constant across layers)
  hipMemsetAsync(cnt, 0, (size_t)((char*)eix - (char*)cnt), stream); // cnt,cnt_d,offs,fc
  deg_k<<<1024, 256, 0, stream>>>(edge_index, cnt, cnt_d);
  scan_k<<<1, 256, 0, stream>>>(cnt_d, offs);
  fill_k<<<1024, 256, 0, stream>>>(edge_index, offs, fc, eix);

  // H0 = gelu(node_emb @ W_lm2gnn + b)
  gemm_k<<<gg, 256, 0, stream>>>(node_emb, W_lm2gnn, b_lm2gnn, nullptr, nullptr,
                                 nullptr, H0, NN, DIN, DD, 1);

  const float* Xcur = H0;
  for (int l = 0; l < 3; ++l) {
    edge_tables_k<<<NT, 256, 0, stream>>>(
        We1 + (size_t)l * NT * DD, be1 + l * DD, g1 + l * DD, bb1 + l * DD,
        We2 + (size_t)l * DD * DD, be2 + l * DD,
        Wk + (size_t)l * 2 * DD * DD + DD * DD, bk + l * DD,
        Wm + (size_t)l * 2 * DD * DD + DD * DD, bm + l * DD, ketab, metab);

    gemm_k<<<gg, 256, 0, stream>>>(Xcur, Wq + (size_t)l * DD * DD, bq + l * DD,
                                   nullptr, nullptr, nullptr, Qb, NN, DD, DD, 0);
    gemm_k<<<gg, 256, 0, stream>>>(Xcur, Wk + (size_t)l * 2 * DD * DD, nullptr,
                                   nullptr, nullptr, nullptr, Kb, NN, DD, DD, 0);

    hipMemsetAsync(smax, 0, (size_t)NN * 4 * 4 * 2, stream);  // smax + den
    score_k<<<2048, 256, 0, stream>>>(Qb, Kb, ketab, edge_index, edge_type, sbuf, smax);
    softmax_k<<<2048, 256, 0, stream>>>(edge_index, sbuf, smax, den);

    // M projection into Qb (Q dead after score_k)
    gemm_k<<<gg, 256, 0, stream>>>(Xcur, Wm + (size_t)l * 2 * DD * DD, nullptr,
                                   nullptr, nullptr, nullptr, Qb, NN, DD, DD, 0);
    // aggregate into Kb (K dead after score_k)
    aggr2_k<<<(NN + 3) / 4, 256, 0, stream>>>(Qb, metab, edge_index, edge_type,
                                              sbuf, den, cnt, offs, eix, Kb);

    // Xl = relu(bn(aggr@Wp1 + bp1)); X = gelu(Xl@Wp2 + bp2)
    gemm_k<<<gg, 256, 0, stream>>>(Kb, Wp1 + (size_t)l * DD * DD, bp1 + l * DD,
                                   nullptr, g2 + l * DD, bb2 + l * DD, Qb, NN, DD, DD, 2);
    gemm_k<<<gg, 256, 0, stream>>>(Qb, Wp2 + (size_t)l * DD * DD, bp2 + l * DD,
                                   nullptr, nullptr, nullptr, Xb, NN, DD, DD, 1);
    Xcur = Xb;
  }

  // hidden = gelu(H0@Wo + bo + X@Wc + bc)
  gemm_k<<<gg, 256, 0, stream>>>(H0, Wo, bo, nullptr, nullptr, nullptr, Kb, NN, DD, DD, 0);
  gemm_k<<<gg, 256, 0, stream>>>(Xb, Wc, bc, Kb, nullptr, nullptr, Qb, NN, DD, DD, 1);

  emis_k<<<1250, 256, 0, stream>>>(Qb, Wt, bt, em);
  viterbi_k<<<1, 256, 0, stream>>>(em, cstart, cend, ctrans, sv, (int*)d_out);
}

// Round 10
// 2930.854 us; speedup vs baseline: 1.1485x; 1.0524x over previous
//
#include <hip/hip_runtime.h>

// Problem constants (fixed by the reference)
#define NN 20000      // nodes
#define EE 240000     // real edges
#define ETOTAL 260000 // edges + self loops
#define DIN 768
#define DD 256
#define NT 9          // tags
// heads = 4, DH = 64

__device__ __forceinline__ unsigned fenc(float x) {
  unsigned u = __float_as_uint(x);
  return (u & 0x80000000u) ? ~u : (u | 0x80000000u);
}
__device__ __forceinline__ float fdec(unsigned e) {
  unsigned u = (e & 0x80000000u) ? (e ^ 0x80000000u) : ~e;
  return __uint_as_float(u);
}
__device__ __forceinline__ float gelu_f(float x) {
  return 0.5f * x * (1.0f + erff(x * 0.70710678118654752440f));
}

// One Viterbi recurrence step (bitwise-exact): 9 grouped v_readlane (hazards
// covered by spacing), 9 v_add, exact v_max3 tree (9->3->1), + emission.
// Scan floor ~150 cyc/step: 9 readlane at quarter-rate (~72cy) + issue.
#define VSTEP(EIN) do {                                                   \
  float f0, f1, f2, f3, f4, f5, f6, f7, f8;                               \
  float q0, q1, q2, q3, q4, q5, q6, q7, q8;                               \
  asm volatile(                                                           \
    "s_nop 1\n\t"                                                         \
    "v_readlane_b32 %[f0], %[sv], 0\n\t"                                  \
    "v_readlane_b32 %[f1], %[sv], 1\n\t"                                  \
    "v_readlane_b32 %[f2], %[sv], 2\n\t"                                  \
    "v_readlane_b32 %[f3], %[sv], 3\n\t"                                  \
    "v_readlane_b32 %[f4], %[sv], 4\n\t"                                  \
    "v_readlane_b32 %[f5], %[sv], 5\n\t"                                  \
    "v_readlane_b32 %[f6], %[sv], 6\n\t"                                  \
    "v_readlane_b32 %[f7], %[sv], 7\n\t"                                  \
    "v_readlane_b32 %[f8], %[sv], 8\n\t"                                  \
    "v_add_f32 %[q0], %[f0], %[u0]\n\t"                                   \
    "v_add_f32 %[q1], %[f1], %[u1]\n\t"                                   \
    "v_add_f32 %[q2], %[f2], %[u2]\n\t"                                   \
    "v_add_f32 %[q3], %[f3], %[u3]\n\t"                                   \
    "v_add_f32 %[q4], %[f4], %[u4]\n\t"                                   \
    "v_add_f32 %[q5], %[f5], %[u5]\n\t"                                   \
    "v_add_f32 %[q6], %[f6], %[u6]\n\t"                                   \
    "v_add_f32 %[q7], %[f7], %[u7]\n\t"                                   \
    "v_add_f32 %[q8], %[f8], %[u8]\n\t"                                   \
    "v_max3_f32 %[q0], %[q0], %[q1], %[q2]\n\t"                           \
    "v_max3_f32 %[q3], %[q3], %[q4], %[q5]\n\t"                           \
    "v_max3_f32 %[q6], %[q6], %[q7], %[q8]\n\t"                           \
    "v_max3_f32 %[q0], %[q0], %[q3], %[q6]\n\t"                           \
    "v_add_f32 %[q0], %[q0], %[e]\n\t"                                    \
    : [f0]"=&s"(f0), [f1]"=&s"(f1), [f2]"=&s"(f2),                        \
      [f3]"=&s"(f3), [f4]"=&s"(f4), [f5]"=&s"(f5),                        \
      [f6]"=&s"(f6), [f7]"=&s"(f7), [f8]"=&s"(f8),                        \
      [q0]"=&v"(q0), [q1]"=&v"(q1), [q2]"=&v"(q2),                        \
      [q3]"=&v"(q3), [q4]"=&v"(q4), [q5]"=&v"(q5),                        \
      [q6]"=&v"(q6), [q7]"=&v"(q7), [q8]"=&v"(q8)                         \
    : [sv]"v"(s), [e]"v"(EIN),                                            \
      [u0]"v"(tcol[0]), [u1]"v"(tcol[1]), [u2]"v"(tcol[2]),               \
      [u3]"v"(tcol[3]), [u4]"v"(tcol[4]), [u5]"v"(tcol[5]),               \
      [u6]"v"(tcol[6]), [u7]"v"(tcol[7]), [u8]"v"(tcol[8]));              \
  s = q0;                                                                 \
  *svp = s; svp += 64;                                                    \
} while (0)

// ---------------- GEMM: C = act(A@B + bias) ----------------
// A: MxK row-major, B: KxN row-major, C: MxN. Requires N%64==0, K%32==0.
// act: 0 = none, 1 = gelu, 2 = bn(g,b) then relu
// 64x64 tile, 4x4/thread (measured best of {64x64, 128x64} on this shape).
__global__ __launch_bounds__(256) void gemm_k(
    const float* __restrict__ A, const float* __restrict__ B,
    const float* __restrict__ bias,
    const float* __restrict__ bng, const float* __restrict__ bnb,
    float* __restrict__ C, int M, int K, int N, int act)
{
  __shared__ float As[32][64];   // transposed A tile: As[k][m]
  __shared__ float Bs[32][64];   // Bs[k][n]
  const int tid = threadIdx.x;
  const int tx = tid & 15, ty = tid >> 4;
  const int m0 = blockIdx.y * 64, n0 = blockIdx.x * 64;
  float acc[4][4];
#pragma unroll
  for (int i = 0; i < 4; ++i)
#pragma unroll
    for (int j = 0; j < 4; ++j) acc[i][j] = 0.f;

  for (int kk = 0; kk < K; kk += 32) {
#pragma unroll
    for (int L = tid; L < 512; L += 256) {   // A tile: 64 rows x 8 float4
      int r = L >> 3, c4 = L & 7;
      int gm = m0 + r;
      float4 v = make_float4(0.f, 0.f, 0.f, 0.f);
      if (gm < M) v = *(const float4*)(A + (size_t)gm * K + kk + c4 * 4);
      As[c4 * 4 + 0][r] = v.x; As[c4 * 4 + 1][r] = v.y;
      As[c4 * 4 + 2][r] = v.z; As[c4 * 4 + 3][r] = v.w;
    }
#pragma unroll
    for (int L = tid; L < 512; L += 256) {   // B tile: 32 rows x 16 float4
      int r = L >> 4, c4 = L & 15;
      *(float4*)&Bs[r][c4 * 4] = *(const float4*)(B + (size_t)(kk + r) * N + n0 + c4 * 4);
    }
    __syncthreads();
#pragma unroll
    for (int k = 0; k < 32; ++k) {
      float a[4], b[4];
      *(float4*)a = *(const float4*)&As[k][ty * 4];
      *(float4*)b = *(const float4*)&Bs[k][tx * 4];
#pragma unroll
      for (int i = 0; i < 4; ++i)
#pragma unroll
        for (int j = 0; j < 4; ++j) acc[i][j] += a[i] * b[j];
    }
    __syncthreads();
  }
  const float bnc = 0.99999500003749968752f;  // 1/sqrt(1+1e-5)
#pragma unroll
  for (int i = 0; i < 4; ++i) {
    int gm = m0 + ty * 4 + i;
    if (gm >= M) continue;
    float o[4];
#pragma unroll
    for (int j = 0; j < 4; ++j) {
      int n = n0 + tx * 4 + j;
      float x = acc[i][j];
      if (bias) x += bias[n];
      if (act == 1) x = gelu_f(x);
      else if (act == 2) { x = x * (bng[n] * bnc) + bnb[n]; x = fmaxf(x, 0.f); }
      o[j] = x;
    }
    *(float4*)(C + (size_t)gm * N + n0 + tx * 4) = *(const float4*)o;
  }
}

// ---------------- fused Q/K/M projections (shared A, 3 B's) ----------------
// C0 = A@B0 + bias0 ; C1 = A@B1 ; C2 = A@B2. K = N = 256 fixed.
__global__ __launch_bounds__(256) void gemm3_k(
    const float* __restrict__ A, const float* __restrict__ B0,
    const float* __restrict__ bias0, const float* __restrict__ B1,
    const float* __restrict__ B2, float* __restrict__ C0,
    float* __restrict__ C1, float* __restrict__ C2, int M)
{
  __shared__ float As[32][64];
  __shared__ float Bs[3][32][64];
  const int tid = threadIdx.x;
  const int tx = tid & 15, ty = tid >> 4;
  const int m0 = blockIdx.y * 64, n0 = blockIdx.x * 64;
  float acc0[4][4], acc1[4][4], acc2[4][4];
#pragma unroll
  for (int i = 0; i < 4; ++i)
#pragma unroll
    for (int j = 0; j < 4; ++j) { acc0[i][j] = 0.f; acc1[i][j] = 0.f; acc2[i][j] = 0.f; }

  for (int kk = 0; kk < DD; kk += 32) {
#pragma unroll
    for (int L = tid; L < 512; L += 256) {   // A tile: 64 rows x 8 float4
      int r = L >> 3, c4 = L & 7;
      int gm = m0 + r;
      float4 v = make_float4(0.f, 0.f, 0.f, 0.f);
      if (gm < M) v = *(const float4*)(A + (size_t)gm * DD + kk + c4 * 4);
      As[c4 * 4 + 0][r] = v.x; As[c4 * 4 + 1][r] = v.y;
      As[c4 * 4 + 2][r] = v.z; As[c4 * 4 + 3][r] = v.w;
    }
#pragma unroll
    for (int L = tid; L < 1536; L += 256) {  // 3 B tiles: 32 rows x 16 float4
      int which = L >> 9, r = (L >> 4) & 31, c4 = L & 15;
      const float* Bp = (which == 0) ? B0 : (which == 1) ? B1 : B2;
      *(float4*)&Bs[which][r][c4 * 4] =
          *(const float4*)(Bp + (size_t)(kk + r) * DD + n0 + c4 * 4);
    }
    __syncthreads();
#pragma unroll
    for (int k = 0; k < 32; ++k) {
      float a[4], b0[4], b1[4], b2[4];
      *(float4*)a = *(const float4*)&As[k][ty * 4];
      *(float4*)b0 = *(const float4*)&Bs[0][k][tx * 4];
      *(float4*)b1 = *(const float4*)&Bs[1][k][tx * 4];
      *(float4*)b2 = *(const float4*)&Bs[2][k][tx * 4];
#pragma unroll
      for (int i = 0; i < 4; ++i)
#pragma unroll
        for (int j = 0; j < 4; ++j) {
          acc0[i][j] += a[i] * b0[j];
          acc1[i][j] += a[i] * b1[j];
          acc2[i][j] += a[i] * b2[j];
        }
    }
    __syncthreads();
  }
#pragma unroll
  for (int i = 0; i < 4; ++i) {
    int gm = m0 + ty * 4 + i;
    if (gm >= M) continue;
    float o0[4], o1[4], o2[4];
#pragma unroll
    for (int j = 0; j < 4; ++j) {
      int n = n0 + tx * 4 + j;
      o0[j] = acc0[i][j] + bias0[n];
      o1[j] = acc1[i][j];
      o2[j] = acc2[i][j];
    }
    *(float4*)(C0 + (size_t)gm * DD + n0 + tx * 4) = *(const float4*)o0;
    *(float4*)(C1 + (size_t)gm * DD + n0 + tx * 4) = *(const float4*)o1;
    *(float4*)(C2 + (size_t)gm * DD + n0 + tx * 4) = *(const float4*)o2;
  }
}

// ---------------- fused two-segment GEMM: C = gelu(A1@B1 + A2@B2 + b1 + b2) -
// K = 256 per segment, N = 256 fixed.
__global__ __launch_bounds__(256) void gemm_cat_k(
    const float* __restrict__ A1, const float* __restrict__ B1,
    const float* __restrict__ bias1, const float* __restrict__ A2,
    const float* __restrict__ B2, const float* __restrict__ bias2,
    float* __restrict__ C, int M)
{
  __shared__ float As[32][64];
  __shared__ float Bs[32][64];
  const int tid = threadIdx.x;
  const int tx = tid & 15, ty = tid >> 4;
  const int m0 = blockIdx.y * 64, n0 = blockIdx.x * 64;
  float acc[4][4];
#pragma unroll
  for (int i = 0; i < 4; ++i)
#pragma unroll
    for (int j = 0; j < 4; ++j) acc[i][j] = 0.f;

  for (int kk = 0; kk < 2 * DD; kk += 32) {
    const float* Ap = (kk < DD) ? A1 : A2;
    const float* Bp = (kk < DD) ? B1 : B2;
    const int ko = kk & (DD - 1);
#pragma unroll
    for (int L = tid; L < 512; L += 256) {
      int r = L >> 3, c4 = L & 7;
      int gm = m0 + r;
      float4 v = make_float4(0.f, 0.f, 0.f, 0.f);
      if (gm < M) v = *(const float4*)(Ap + (size_t)gm * DD + ko + c4 * 4);
      As[c4 * 4 + 0][r] = v.x; As[c4 * 4 + 1][r] = v.y;
      As[c4 * 4 + 2][r] = v.z; As[c4 * 4 + 3][r] = v.w;
    }
#pragma unroll
    for (int L = tid; L < 512; L += 256) {
      int r = L >> 4, c4 = L & 15;
      *(float4*)&Bs[r][c4 * 4] = *(const float4*)(Bp + (size_t)(ko + r) * DD + n0 + c4 * 4);
    }
    __syncthreads();
#pragma unroll
    for (int k = 0; k < 32; ++k) {
      float a[4], b[4];
      *(float4*)a = *(const float4*)&As[k][ty * 4];
      *(float4*)b = *(const float4*)&Bs[k][tx * 4];
#pragma unroll
      for (int i = 0; i < 4; ++i)
#pragma unroll
        for (int j = 0; j < 4; ++j) acc[i][j] += a[i] * b[j];
    }
    __syncthreads();
  }
#pragma unroll
  for (int i = 0; i < 4; ++i) {
    int gm = m0 + ty * 4 + i;
    if (gm >= M) continue;
    float o[4];
#pragma unroll
    for (int j = 0; j < 4; ++j) {
      int n = n0 + tx * 4 + j;
      o[j] = gelu_f(acc[i][j] + bias1[n] + bias2[n]);
    }
    *(float4*)(C + (size_t)gm * DD + n0 + tx * 4) = *(const float4*)o;
  }
}

// ---------------- per-layer edge-type tables (9 types) ----------------
__global__ __launch_bounds__(256) void edge_tables_k(
    const float* __restrict__ We1l, const float* __restrict__ be1l,
    const float* __restrict__ g1l, const float* __restrict__ bb1l,
    const float* __restrict__ We2l, const float* __restrict__ be2l,
    const float* __restrict__ WkEl, const float* __restrict__ bkl,
    const float* __restrict__ WmEl, const float* __restrict__ bml,
    float* __restrict__ ketab, float* __restrict__ metab)
{
  __shared__ float r_s[DD];
  __shared__ float e_s[DD];
  const int t = blockIdx.x, d = threadIdx.x;
  const float bnc = 0.99999500003749968752f;
  float pre = We1l[t * DD + d] + be1l[d];
  float bnv = pre * (g1l[d] * bnc) + bb1l[d];
  r_s[d] = fmaxf(bnv, 0.f);
  __syncthreads();
  float acc = 0.f;
  for (int c = 0; c < DD; ++c) acc += r_s[c] * We2l[c * DD + d];
  e_s[d] = acc + be2l[d];
  __syncthreads();
  float ka = 0.f, ma = 0.f;
  for (int c = 0; c < DD; ++c) {
    float ec = e_s[c];
    ka += ec * WkEl[c * DD + d];
    ma += ec * WmEl[c * DD + d];
  }
  ketab[t * DD + d] = ka + bkl[d];
  metab[t * DD + d] = ma + bml[d];
}

// ---------------- degree counts ----------------
__global__ void deg_k(const int* __restrict__ ei, int* __restrict__ cnt,
                      int* __restrict__ cnt_d)
{
  for (int e = blockIdx.x * blockDim.x + threadIdx.x; e < EE; e += gridDim.x * blockDim.x) {
    atomicAdd(&cnt[ei[e]], 1);        // src out-degree (real edges)
    atomicAdd(&cnt_d[ei[EE + e]], 1); // dst in-degree (real edges)
  }
}

// ---------------- exclusive scan over cnt_d (single block) ----------------
__global__ __launch_bounds__(256) void scan_k(const int* __restrict__ c,
                                              int* __restrict__ offs)
{
  __shared__ int part[257];
  const int tid = threadIdx.x;
  const int CH = (NN + 255) / 256;
  int a = tid * CH, b = a + CH; if (b > NN) b = NN;
  int s = 0;
  for (int i = a; i < b; ++i) s += c[i];
  part[tid] = s;
  __syncthreads();
  if (tid == 0) {
    int r = 0;
    for (int i = 0; i < 256; ++i) { int v = part[i]; part[i] = r; r += v; }
    part[256] = r;
  }
  __syncthreads();
  int r = part[tid];
  for (int i = a; i < b; ++i) { offs[i] = r; r += c[i]; }
  if (tid == 255) offs[NN] = part[256];
}

// ---------------- CSR fill (by dst) ----------------
__global__ void fill_k(const int* __restrict__ ei, const int* __restrict__ offs,
                       int* __restrict__ fc, int* __restrict__ eix)
{
  for (int e = blockIdx.x * blockDim.x + threadIdx.x; e < EE; e += gridDim.x * blockDim.x) {
    int d = ei[EE + e];
    int p = offs[d] + atomicAdd(&fc[d], 1);
    eix[p] = e;
  }
}

// ---------------- pass A: attention scores + segment max over src ----------
__global__ __launch_bounds__(256) void score_k(
    const float* __restrict__ Q, const float* __restrict__ Kn,
    const float* __restrict__ ketab, const int* __restrict__ ei,
    const int* __restrict__ et, float* __restrict__ sbuf,
    unsigned* __restrict__ smax)
{
  __shared__ float ke_s[NT * DD];
  for (int i = threadIdx.x; i < NT * DD; i += 256) ke_s[i] = ketab[i];
  __syncthreads();
  const int lane = threadIdx.x & 63, wave = threadIdx.x >> 6;
  const float4* Q4 = (const float4*)Q;
  const float4* K4 = (const float4*)Kn;
  for (int e = blockIdx.x * 4 + wave; e < ETOTAL; e += gridDim.x * 4) {
    int src, dst, t;
    if (e < EE) { src = ei[e]; dst = ei[EE + e]; t = et[e]; }
    else { src = dst = e - EE; t = NT - 1; }
    float4 q = Q4[src * 64 + lane];
    float4 k = K4[dst * 64 + lane];
    float4 ke = *(const float4*)(ke_s + t * DD + lane * 4);
    float p = q.x * (k.x + ke.x) + q.y * (k.y + ke.y) +
              q.z * (k.z + ke.z) + q.w * (k.w + ke.w);
    p += __shfl_xor(p, 8); p += __shfl_xor(p, 4);
    p += __shfl_xor(p, 2); p += __shfl_xor(p, 1);
    if ((lane & 15) == 0) {
      int h = lane >> 4;
      float s = p * 0.125f;            // / sqrt(64)
      sbuf[e * 4 + h] = s;
      atomicMax(smax + src * 4 + h, fenc(s));
    }
  }
}

// ---------------- pass B: exp(s - max) and segment sum over src ------------
__global__ void softmax_k(const int* __restrict__ ei, float* __restrict__ sbuf,
                          const unsigned* __restrict__ smax, float* __restrict__ den)
{
  for (int idx = blockIdx.x * blockDim.x + threadIdx.x; idx < ETOTAL * 4;
       idx += gridDim.x * blockDim.x) {
    int e = idx >> 2, h = idx & 3;
    int src = (e < EE) ? ei[e] : e - EE;
    float s = sbuf[idx];
    float ex = expf(s - fdec(smax[src * 4 + h]));
    sbuf[idx] = ex;
    atomicAdd(den + src * 4 + h, ex);
  }
}

// ---------------- pass C: atomic-free aggregation (wave per dst) -----------
__global__ __launch_bounds__(256) void aggr2_k(
    const float* __restrict__ Mn, const float* __restrict__ metab,
    const int* __restrict__ ei, const int* __restrict__ et,
    const float* __restrict__ sbuf, const float* __restrict__ den,
    const int* __restrict__ cnt, const int* __restrict__ offs,
    const int* __restrict__ eix, float* __restrict__ aggr)
{
  __shared__ float me_s[NT * DD];
  for (int i = threadIdx.x; i < NT * DD; i += 256) me_s[i] = metab[i];
  __syncthreads();
  const int lane = threadIdx.x & 63, wave = threadIdx.x >> 6;
  const int h = lane >> 4;
  const float4* M4 = (const float4*)Mn;
  int dst = blockIdx.x * 4 + wave;
  if (dst >= NN) return;
  float4 acc;
  {
    // self-loop (edge id EE+dst, type NT-1)
    float ex = sbuf[(EE + dst) * 4 + h];
    float dn = den[dst * 4 + h];
    float alpha = ex / (dn + 1e-16f) * (float)(cnt[dst] + 1);
    float4 m = M4[dst * 64 + lane];
    float4 me = *(const float4*)(me_s + (NT - 1) * DD + lane * 4);
    acc.x = (m.x + me.x) * alpha; acc.y = (m.y + me.y) * alpha;
    acc.z = (m.z + me.z) * alpha; acc.w = (m.w + me.w) * alpha;
  }
  int o1 = offs[dst + 1];
  for (int o = offs[dst]; o < o1; ++o) {
    int e = eix[o];
    int src = ei[e], t = et[e];
    float ex = sbuf[e * 4 + h];
    float dn = den[src * 4 + h];
    float alpha = ex / (dn + 1e-16f) * (float)(cnt[src] + 1);
    float4 m = M4[src * 64 + lane];
    float4 me = *(const float4*)(me_s + t * DD + lane * 4);
    acc.x += (m.x + me.x) * alpha; acc.y += (m.y + me.y) * alpha;
    acc.z += (m.z + me.z) * alpha; acc.w += (m.w + me.w) * alpha;
  }
  ((float4*)aggr)[dst * 64 + lane] = acc;
}

// ---------------- emissions: em = hidden @ Wt + bt  (256 -> 9) -------------
__global__ __launch_bounds__(256) void emis_k(
    const float* __restrict__ hidden, const float* __restrict__ Wt,
    const float* __restrict__ bt, float* __restrict__ em)
{
  __shared__ float wt_s[DD * NT];
  for (int i = threadIdx.x; i < DD * NT; i += 256) wt_s[i] = Wt[i];
  __syncthreads();
  const int lane = threadIdx.x & 63, wave = threadIdx.x >> 6;
  const float4* H4 = (const float4*)hidden;
  for (int n = blockIdx.x * 4 + wave; n < NN; n += gridDim.x * 4) {
    float4 h = H4[n * 64 + lane];
    const float* w0 = wt_s + (lane * 4) * NT;
    float p[NT];
#pragma unroll
    for (int t = 0; t < NT; ++t)
      p[t] = h.x * w0[t] + h.y * w0[NT + t] + h.z * w0[2 * NT + t] + h.w * w0[3 * NT + t];
#pragma unroll
    for (int m = 32; m >= 1; m >>= 1)
#pragma unroll
      for (int t = 0; t < NT; ++t) p[t] += __shfl_xor(p[t], m);
    if (lane == 0) {
#pragma unroll
      for (int t = 0; t < NT; ++t) em[n * NT + t] = p[t] + bt[t];
    }
  }
}

// ---------------- Viterbi decode (single block) ----------------------------
// Forward scan: wave0, lanes replicate states j=min(lane&15,8). Recurrence =
// VSTEP asm block (readlane + add + exact max3 tree -> bitwise identical).
// Emission LDS reads batched 4-at-a-time, issued 8 steps ahead. Score rows
// stored stride-64; backpointers recomputed bitwise-exactly in the parallel
// backtrack (first-index tie rule = jnp.argmax).
__global__ __launch_bounds__(256) void viterbi_k(
    const float* __restrict__ em, const float* __restrict__ cstart,
    const float* __restrict__ cend, const float* __restrict__ ctrans,
    float* __restrict__ sv, int* __restrict__ outp)
{
  const int VCS = 512;
  const int NCH = (NN + VCS - 1) / VCS;
  __shared__ float embuf[2][VCS * NT + 32];
  __shared__ float trT[NT * 16];              // trT[j*16+i] = trans[i][j]
  __shared__ float scf[NT];
  __shared__ unsigned char fmaps[256][NT];
  __shared__ unsigned char ends_s[256];
  __shared__ int last_s;
  const int tid = threadIdx.x, lane = tid & 63, wave = tid >> 6;
  const int jl = min(lane & 15, NT - 1);

  for (int i = tid; i < VCS * NT; i += 256) embuf[0][i] = em[i];
  if (tid < NT * NT) trT[(tid % NT) * 16 + (tid / NT)] = ctrans[tid];
  __syncthreads();

  float tcol[NT];   // tcol[i] = trans[i][jl]
  float s = 0.f;
  if (wave == 0) {
#pragma unroll
    for (int i = 0; i < NT; ++i) tcol[i] = ctrans[i * NT + jl];
    s = cstart[jl] + embuf[0][jl];
    sv[lane] = s;                 // row t=0, stride 64
  }

  for (int c = 0; c < NCH; ++c) {
    if (wave > 0) {
      if (c + 1 < NCH) {
        int base = (c + 1) * VCS * NT;
        int n2 = VCS * NT;
        if (base + n2 > NN * NT) n2 = NN * NT - base;
        for (int i = tid - 64; i < n2; i += 192) embuf[(c + 1) & 1][i] = em[base + i];
      }
    } else {
      const float* eb = embuf[c & 1];
      int tbeg = (c == 0) ? 1 : c * VCS;
      int tend = (c + 1) * VCS; if (tend > NN) tend = NN;
      int off = tbeg - c * VCS;
      int nsteps = tend - tbeg;
      float* svp = sv + (size_t)tbeg * 64 + lane;
      int i = 0;
      if (nsteps >= 12) {
        // software pipeline: a* = steps i..i+3, b* = steps i+4..i+7
        float a0 = eb[(off + 0) * NT + jl], a1 = eb[(off + 1) * NT + jl];
        float a2 = eb[(off + 2) * NT + jl], a3 = eb[(off + 3) * NT + jl];
        float b0 = eb[(off + 4) * NT + jl], b1 = eb[(off + 5) * NT + jl];
        float b2 = eb[(off + 6) * NT + jl], b3 = eb[(off + 7) * NT + jl];
        int nblk = (nsteps - 8) / 4;
        for (int bk = 0; bk < nblk; ++bk) {
          int lo = off + 8 + bk * 4;           // lo+3 <= off+nsteps-1: in-range
          float n0 = eb[(lo + 0) * NT + jl];
          float n1 = eb[(lo + 1) * NT + jl];
          float n2v = eb[(lo + 2) * NT + jl];
          float n3 = eb[(lo + 3) * NT + jl];
          VSTEP(a0); VSTEP(a1); VSTEP(a2); VSTEP(a3);
          a0 = b0; a1 = b1; a2 = b2; a3 = b3;
          b0 = n0; b1 = n1; b2 = n2v; b3 = n3;
        }
        i = nblk * 4;
        // drain the 8 pipelined emissions (rem = nsteps - i is in [8,11])
        VSTEP(a0); VSTEP(a1); VSTEP(a2); VSTEP(a3);
        VSTEP(b0); VSTEP(b1); VSTEP(b2); VSTEP(b3);
        i += 8;
      }
      for (; i < nsteps; ++i) {                // <=3 scalar tail steps
        float e0 = eb[(off + i) * NT + jl];
        VSTEP(e0);
      }
    }
    __syncthreads();
  }

  if (wave == 0 && lane < NT) scf[lane] = s + cend[lane];
  __syncthreads();
  if (tid == 0) {
    float bv = scf[0]; int bi = 0;
    for (int j = 1; j < NT; ++j) if (scf[j] > bv) { bv = scf[j]; bi = j; }
    last_s = bi;
  }
  __syncthreads();

  // backtrack: per-range end->start maps via exact bp recomputation
  const int RL = 79;
  int a = 1 + tid * RL;
  int b = a + RL; if (b > NN) b = NN;
  bool active = (a < NN);
  if (active) {
    int x[NT];
#pragma unroll
    for (int j = 0; j < NT; ++j) x[j] = j;
    for (int t = b - 1; t >= a; --t) {
      const float* sp = sv + (size_t)(t - 1) * 64;
      float sr[NT];
#pragma unroll
      for (int i = 0; i < NT; ++i) sr[i] = sp[i];
#pragma unroll
      for (int j = 0; j < NT; ++j) {
        const float* tcx = trT + x[j] * 16;
        float bv = sr[0] + tcx[0]; int bi = 0;
#pragma unroll
        for (int i = 1; i < NT; ++i) {
          float cv = sr[i] + tcx[i];
          if (cv > bv) { bv = cv; bi = i; }
        }
        x[j] = bi;
      }
    }
#pragma unroll
    for (int j = 0; j < NT; ++j) fmaps[tid][j] = (unsigned char)x[j];
  }
  __syncthreads();
  if (tid == 0) {
    int x = last_s;
    for (int k = 255; k >= 0; --k) {
      ends_s[k] = (unsigned char)x;
      int ak = 1 + k * RL;
      if (ak < NN) x = fmaps[k][x];
    }
  }
  __syncthreads();
  if (active) {
    int x = ends_s[tid];
    outp[b - 1] = x;
    for (int t = b - 1; t >= a; --t) {
      const float* sp = sv + (size_t)(t - 1) * 64;
      const float* tcx = trT + x * 16;
      float bv = sp[0] + tcx[0]; int bi = 0;
#pragma unroll
      for (int i = 1; i < NT; ++i) {
        float cv = sp[i] + tcx[i];
        if (cv > bv) { bv = cv; bi = i; }
      }
      x = bi;
      outp[t - 1] = x;
    }
  }
}

// ---------------------------------------------------------------------------
extern "C" void kernel_launch(void* const* d_in, const int* in_sizes, int n_in,
                              void* d_out, int out_size, void* d_ws, size_t ws_size,
                              hipStream_t stream)
{
  const float* node_emb = (const float*)d_in[0];
  const int* edge_index = (const int*)d_in[1];
  const int* edge_type = (const int*)d_in[2];
  // d_in[3] = tag_gt (unused by reference)
  const float* W_lm2gnn = (const float*)d_in[4];
  const float* b_lm2gnn = (const float*)d_in[5];
  const float* We1 = (const float*)d_in[6];
  const float* be1 = (const float*)d_in[7];
  const float* g1 = (const float*)d_in[8];
  const float* bb1 = (const float*)d_in[9];
  const float* We2 = (const float*)d_in[10];
  const float* be2 = (const float*)d_in[11];
  const float* Wq = (const float*)d_in[12];
  const float* bq = (const float*)d_in[13];
  const float* Wk = (const float*)d_in[14];
  const float* bk = (const float*)d_in[15];
  const float* Wm = (const float*)d_in[16];
  const float* bm = (const float*)d_in[17];
  const float* Wp1 = (const float*)d_in[18];
  const float* bp1 = (const float*)d_in[19];
  const float* g2 = (const float*)d_in[20];
  const float* bb2 = (const float*)d_in[21];
  const float* Wp2 = (const float*)d_in[22];
  const float* bp2 = (const float*)d_in[23];
  const float* Wo = (const float*)d_in[24];
  const float* bo = (const float*)d_in[25];
  const float* Wc = (const float*)d_in[26];
  const float* bc = (const float*)d_in[27];
  const float* Wt = (const float*)d_in[28];
  const float* bt = (const float*)d_in[29];
  const float* cstart = (const float*)d_in[30];
  const float* cend = (const float*)d_in[31];
  const float* ctrans = (const float*)d_in[32];

  // Workspace layout: 5 big node buffers + small region.
  const size_t NB = (size_t)NN * DD * sizeof(float); // 20,480,000
  char* w = (char*)d_ws;
  float* H0 = (float*)(w + 0 * NB);
  float* Xb = (float*)(w + 1 * NB);
  float* Qb = (float*)(w + 2 * NB);   // Q, then Xl, then hidden
  float* Kb = (float*)(w + 3 * NB);   // K, then aggr
  float* Mb = (float*)(w + 4 * NB);   // M
  char* sm = w + 5 * NB;
  size_t smo = 0;
  auto alloc = [&](size_t bytes) { char* p = sm + smo; smo += (bytes + 255) & ~255ull; return p; };
  float* sbuf = (float*)alloc((size_t)ETOTAL * 4 * 4);
  unsigned* smax = (unsigned*)alloc((size_t)NN * 4 * 4);   // contiguous with den
  float* den = (float*)alloc((size_t)NN * 4 * 4);
  int* cnt = (int*)alloc((size_t)NN * 4);                  // cnt..fc zeroed together
  int* cnt_d = (int*)alloc((size_t)NN * 4);
  int* offs = (int*)alloc((size_t)(NN + 1) * 4);
  int* fc = (int*)alloc((size_t)NN * 4);
  int* eix = (int*)alloc((size_t)EE * 4);
  float* ketab = (float*)alloc((size_t)NT * DD * 4);
  float* metab = (float*)alloc((size_t)NT * DD * 4);
  float* em = (float*)alloc((size_t)NN * NT * 4);
  float* sv = (float*)alloc(((size_t)NN * 64 + 64) * 4);   // stride-64 score rows
  const size_t needed = 5 * NB + smo;
  if (ws_size < needed) return;  // fail visibly rather than corrupt

  dim3 gg(DD / 64, (NN + 63) / 64);

  // degree counts + dst-CSR (edge structure constant across layers)
  hipMemsetAsync(cnt, 0, (size_t)((char*)eix - (char*)cnt), stream); // cnt,cnt_d,offs,fc
  deg_k<<<1024, 256, 0, stream>>>(edge_index, cnt, cnt_d);
  scan_k<<<1, 256, 0, stream>>>(cnt_d, offs);
  fill_k<<<1024, 256, 0, stream>>>(edge_index, offs, fc, eix);

  // H0 = gelu(node_emb @ W_lm2gnn + b)
  gemm_k<<<gg, 256, 0, stream>>>(node_emb, W_lm2gnn, b_lm2gnn, nullptr,
                                 nullptr, H0, NN, DIN, DD, 1);

  const float* Xcur = H0;
  for (int l = 0; l < 3; ++l) {
    edge_tables_k<<<NT, 256, 0, stream>>>(
        We1 + (size_t)l * NT * DD, be1 + l * DD, g1 + l * DD, bb1 + l * DD,
        We2 + (size_t)l * DD * DD, be2 + l * DD,
        Wk + (size_t)l * 2 * DD * DD + DD * DD, bk + l * DD,
        Wm + (size_t)l * 2 * DD * DD + DD * DD, bm + l * DD, ketab, metab);

    // fused Q/K/M projections (A-tile staged once)
    gemm3_k<<<gg, 256, 0, stream>>>(Xcur, Wq + (size_t)l * DD * DD, bq + l * DD,
                                    Wk + (size_t)l * 2 * DD * DD,
                                    Wm + (size_t)l * 2 * DD * DD,
                                    Qb, Kb, Mb, NN);

    hipMemsetAsync(smax, 0, (size_t)NN * 4 * 4 * 2, stream);  // smax + den
    score_k<<<2048, 256, 0, stream>>>(Qb, Kb, ketab, edge_index, edge_type, sbuf, smax);
    softmax_k<<<2048, 256, 0, stream>>>(edge_index, sbuf, smax, den);

    // aggregate into Kb (K dead after score_k)
    aggr2_k<<<(NN + 3) / 4, 256, 0, stream>>>(Mb, metab, edge_index, edge_type,
                                              sbuf, den, cnt, offs, eix, Kb);

    // Xl = relu(bn(aggr@Wp1 + bp1)); X = gelu(Xl@Wp2 + bp2)
    gemm_k<<<gg, 256, 0, stream>>>(Kb, Wp1 + (size_t)l * DD * DD, bp1 + l * DD,
                                   g2 + l * DD, bb2 + l * DD, Qb, NN, DD, DD, 2);
    gemm_k<<<gg, 256, 0, stream>>>(Qb, Wp2 + (size_t)l * DD * DD, bp2 + l * DD,
                                   nullptr, nullptr, Xb, NN, DD, DD, 1);
    Xcur = Xb;
  }

  // hidden = gelu(H0@Wo + bo + X@Wc + bc) — fused K=512 two-segment gemm
  gemm_cat_k<<<gg, 256, 0, stream>>>(H0, Wo, bo, Xb, Wc, bc, Qb, NN);

  emis_k<<<1250, 256, 0, stream>>>(Qb, Wt, bt, em);
  viterbi_k<<<1, 256, 0, stream>>>(em, cstart, cend, ctrans, sv, (int*)d_out);
}